// Round 9
// baseline (2630.902 us; speedup 1.0000x reference)
//
#include <hip/hip_runtime.h>

// ---------------------------------------------------------------------------
// self_LSTM_sparse_attn — MI355X persistent-kernel, round 9.
//
// R8 post-mortem: 7.0us/step @ 2 waves/SIMD. Critical-wave chain still pays:
// 4-way random LIC gather + S2 barrier + replicated tail. This round:
//   (1) gather deleted: top-5 entries carry their memory VALUES (qA,qB pairs)
//       through the ins5 shifts. New entrant's value = ho(i-1) = registers
//       (po0,po1) from last step. m = sum w_k*q_k, zero loads, bit-identical.
//   (2) S2 deleted: per-producer-wave flags. Wave0 (mem) and wave2 (psum)
//       each drain own stores (vmcnt(0)) then publish flag2[2g]/flag2[2g+1];
//       consumers poll the pair with one dwordx2 sc0 sc1 load.
//   (3) tail only on waves 0..2; waves 3..7 skip to x-overlap/poll. LDS WAR
//       hazard (was S2's job) fixed by parity double-buffered red2/psum
//       (skew <=1 step guaranteed by S1).
//
// Carried invariants (R5-R8-verified): cross-WG data write-once per step;
// cross-WG stores direct to LIC via sc0 sc1, no fences anywhere; flags
// stored only after vmcnt(0) drain of the owning wave's data stores;
// per-wave producer wait (wave kqu's psum slots AND mem dims both produced
// by WGs [32kqu,32kqu+32)).
// Algorithm (R2-R8-verified): s_h cancels in attention weights; w <=4-sparse;
// WG g owns h dims {2g,2g+1}; mem[i] == h_out(i-1); incremental top-5.
// ---------------------------------------------------------------------------

#define T_N 256
#define B_N 64
#define I_N 256
#define H_N 512
#define C_N 64
#define EPSF 1e-7f

typedef float v4f __attribute__((ext_vector_type(4)));
typedef float v2f __attribute__((ext_vector_type(2)));
typedef unsigned v2u __attribute__((ext_vector_type(2)));

// ws layout (float offsets). Packed layouts: [..][k4][b][u] u=k&3.
#define XT4_F   0u          // [T][64][64][4]    x packed          (4,194,304)
#define MEM4_F  4194304u    // [T+1][128][64][4] h_out history     (8,421,376)
#define MSEQ4_F 12615680u   // [T][128][64][4]   m_seq             (8,388,608)
#define PSUM4_F 21004288u   // [T+1][64][64][4]  score partials, write-once (4,210,688)
#define FCWT_F  25214976u   // [2H][C] fc_w transposed             (65,536)
#define FLAG_F  25280512u   // [256][2] flags: {mem-ready, psum-ready} u32 (512)
#define TOT_F   25281024u

__device__ __forceinline__ float sigf(float x) { return 1.0f / (1.0f + expf(-x)); }

// direct-to-LIC (coherence point) ops — no fences needed anywhere.
__device__ __forceinline__ void st_lic_f32(float* p, float v) {
  asm volatile("global_store_dword %0, %1, off sc0 sc1" :: "v"(p), "v"(v) : "memory");
}
__device__ __forceinline__ void st_lic_f32x2(float* p, v2f v) {
  asm volatile("global_store_dwordx2 %0, %1, off sc0 sc1" :: "v"(p), "v"(v) : "memory");
}
__device__ __forceinline__ void st_lic_u32(unsigned* p, unsigned v) {
  asm volatile("global_store_dword %0, %1, off sc0 sc1" :: "v"(p), "v"(v) : "memory");
}
__device__ __forceinline__ v2u ld_lic_u32x2(const unsigned* p) {
  v2u r;
  asm volatile("global_load_dwordx2 %0, %1, off sc0 sc1\n\ts_waitcnt vmcnt(0)"
               : "=v"(r) : "v"(p) : "memory");
  return r;
}

// insert (s, a0, a1) into descending top-5; slots 0..3 carry values (qa,qb)
__device__ __forceinline__ void ins5v(float s, float a0, float a1,
    float& v0, float& v1, float& v2, float& v3, float& v4,
    float& qa0, float& qb0, float& qa1, float& qb1,
    float& qa2, float& qb2, float& qa3, float& qb3) {
  if (s > v4) {
    if (s > v0) {
      v4=v3; v3=v2; qa3=qa2; qb3=qb2; v2=v1; qa2=qa1; qb2=qb1;
      v1=v0; qa1=qa0; qb1=qb0; v0=s; qa0=a0; qb0=a1;
    } else if (s > v1) {
      v4=v3; v3=v2; qa3=qa2; qb3=qb2; v2=v1; qa2=qa1; qb2=qb1;
      v1=s; qa1=a0; qb1=a1;
    } else if (s > v2) {
      v4=v3; v3=v2; qa3=qa2; qb3=qb2; v2=s; qa2=a0; qb2=a1;
    } else if (s > v3) {
      v4=v3; v3=s; qa3=a0; qb3=a1;
    } else {
      v4=s;
    }
  }
}

__global__ void poison_k(float* out, int n) {
  int i = blockIdx.x * 256 + threadIdx.x;
  if (i < n) out[i] = __int_as_float(0x7fc00000);
}

// blocks 0..1023: x -> xT4 packed; blocks 1024..1039: fc_w -> fcwT[d][c]
__global__ void init_k(const float* __restrict__ x, const float* __restrict__ fc_w,
                       float* __restrict__ ws) {
  __shared__ float tile[64][65];
  const int blk = blockIdx.x, tid = threadIdx.x;
  if (blk < 1024) {
    const int t = blk >> 2, k0 = (blk & 3) * 64;
    for (int u = tid; u < 4096; u += 256) {
      int bb = u >> 6, kk = u & 63;
      tile[kk][bb] = x[((unsigned)t * 64u + bb) * 256u + k0 + kk];
    }
    __syncthreads();
    for (int u = tid; u < 4096; u += 256) {
      int kk = u >> 6, bb = u & 63;
      int k = k0 + kk;
      ws[XT4_F + (unsigned)t * 16384u + (unsigned)(k >> 2) * 256u
         + (unsigned)bb * 4u + (unsigned)(k & 3)] = tile[kk][bb];
    }
  } else {
    const int d0 = (blk - 1024) * 64;
    for (int u = tid; u < 4096; u += 256) {
      int cc = u >> 6, dd = u & 63;
      tile[dd][cc] = fc_w[(unsigned)cc * 1024u + d0 + dd];
    }
    __syncthreads();
    for (int u = tid; u < 4096; u += 256) {
      int dd = u >> 6, cc = u & 63;
      ws[FCWT_F + (unsigned)(d0 + dd) * 64u + cc] = tile[dd][cc];
    }
  }
}

__launch_bounds__(512, 1)
__global__ void lstm_main(const float* __restrict__ W_ih, const float* __restrict__ W_hh,
                          const float* __restrict__ b_ih, const float* __restrict__ b_hh,
                          const float* __restrict__ w_t, float* __restrict__ ws) {
  __shared__ float Wx[I_N][8];              // 8 KB  weight rows, LDS-resident
  __shared__ float Wh[H_N][8];              // 16 KB
  __shared__ float red2[2][8][4][B_N][2];   // 32 KB gate partials, parity dbuf
  __shared__ float psum[2][8][B_N];         // 4 KB  score partials, parity dbuf

  const int g = blockIdx.x;
  const int tid = threadIdx.x;
  const int b = tid & 63;
  const int kqu = __builtin_amdgcn_readfirstlane(tid >> 6);  // wave id 0..7

  unsigned int* flags = (unsigned int*)(ws + FLAG_F);

  // stage weights (resident all steps)
  for (int idx = tid; idx < 8 * I_N; idx += 512) {
    int rr = idx >> 8, k = idx & (I_N - 1);
    int grow = (rr >> 1) * H_N + 2 * g + (rr & 1);   // rr = gate*2 + jj
    Wx[k][rr] = W_ih[grow * I_N + k];
  }
  for (int idx = tid; idx < 8 * H_N; idx += 512) {
    int rr = idx >> 9, k = idx & (H_N - 1);
    int grow = (rr >> 1) * H_N + 2 * g + (rr & 1);
    Wh[k][rr] = W_hh[grow * H_N + k];
  }
  float bias_r[8];
  #pragma unroll
  for (int r = 0; r < 8; ++r) {
    int grow = (r >> 1) * H_N + 2 * g + (r & 1);
    bias_r[r] = b_ih[grow] + b_hh[grow];
  }
  const float wt20 = w_t[H_N + 2 * g];
  const float wt21 = w_t[H_N + 2 * g + 1];
  __syncthreads();

  // replicated tail state on waves 0..2 (bit-identical streams)
  float cs0 = 0.0f, cs1 = 0.0f;                 // LSTM c-state
  float po0 = 0.0f, po1 = 0.0f;                 // ho(i-1) == mem[i] (own dims)
  float v0 = -3e38f, v1 = -3e38f, v2 = -3e38f, v3 = -3e38f, v4 = -3e38f;
  float qa0 = 0, qb0 = 0, qa1 = 0, qb1 = 0, qa2 = 0, qb2 = 0, qa3 = 0, qb3 = 0;
  float mn = 3e38f;

  const unsigned hoff0 = (unsigned)(g >> 1) * 256u + (unsigned)b * 4u + (unsigned)((g & 1) * 2);

  // prologue: x-part of step 0's matvec (k-eighth per wave)
  float xacc[8];
  #pragma unroll
  for (int r = 0; r < 8; ++r) xacc[r] = 0.0f;
  {
    const v4f* xp = (const v4f*)(ws + XT4_F) + (unsigned)(kqu * 8) * 64u + b;
    v4f xv[8];
    #pragma unroll
    for (int j = 0; j < 8; ++j) xv[j] = xp[j * 64];
    #pragma unroll
    for (int j = 0; j < 8; ++j) {
      #pragma unroll
      for (int u = 0; u < 4; ++u) {
        float v = xv[j][u];
        const float* wr = &Wx[kqu * 32 + 4 * j + u][0];
        #pragma unroll
        for (int r = 0; r < 8; ++r) xacc[r] += v * wr[r];
      }
    }
  }

  for (int i = 0; i < T_N; ++i) {
    const int par = i & 1;

    // ---- S0: per-wave producer wait. Wave kqu's psum slots AND mem dims
    // are both produced by WGs [32kqu, 32kqu+32). Poll {mem,psum} flag pair. ----
    if (i > 0) {
      const unsigned* fp = flags + 2u * (unsigned)(kqu * 32 + (b & 31));
      for (;;) {
        v2u f = ld_lic_u32x2(fp);
        if (f[0] >= (unsigned)i && f[1] >= (unsigned)i) break;
        __builtin_amdgcn_s_sleep(1);
      }
    }

    // ---- Phase A: batched vector loads; weights broadcast from LDS ----
    v4f pv[8];
    {
      const v4f* pp = (const v4f*)(ws + PSUM4_F) + (unsigned)i * 4096u
                      + (unsigned)(kqu * 8) * 64u + b;
      #pragma unroll
      for (int j = 0; j < 8; ++j) pv[j] = pp[j * 64];
    }
    v4f hv[16];
    {
      const v4f* hp = (const v4f*)(ws + MEM4_F) + (unsigned)i * 8192u
                      + (unsigned)(kqu * 16) * 64u + b;  // mem[i] == h_out(i-1)
      #pragma unroll
      for (int j = 0; j < 16; ++j) hv[j] = hp[j * 64];
    }
    float ps = 0.0f;
    #pragma unroll
    for (int j = 0; j < 8; ++j) ps += (pv[j][0] + pv[j][1]) + (pv[j][2] + pv[j][3]);
    psum[par][kqu][b] = ps;

    float acc[8];
    #pragma unroll
    for (int r = 0; r < 8; ++r) acc[r] = xacc[r];
    #pragma unroll
    for (int j = 0; j < 16; ++j) {
      #pragma unroll
      for (int u = 0; u < 4; ++u) {
        float v = hv[j][u];
        const float* wr = &Wh[kqu * 64 + 4 * j + u][0];
        #pragma unroll
        for (int r = 0; r < 8; ++r) acc[r] += v * wr[r];
      }
    }
    #pragma unroll
    for (int p = 0; p < 4; ++p) {
      red2[par][kqu][p][b][0] = acc[2 * p];
      red2[par][kqu][p][b][1] = acc[2 * p + 1];
    }
    __syncthreads();  // S1 (the only barrier)

    // ---- tail: waves 0..2 only (replicated, bit-identical) ----
    if (kqu < 3) {
      float sc = ((psum[par][0][b] + psum[par][1][b]) + (psum[par][2][b] + psum[par][3][b]))
               + ((psum[par][4][b] + psum[par][5][b]) + (psum[par][6][b] + psum[par][7][b]));
      ins5v(sc, po0, po1, v0, v1, v2, v3, v4,
            qa0, qb0, qa1, qb1, qa2, qb2, qa3, qb3);
      mn = fminf(mn, sc);
      float delta = ((i + 1) <= 5 ? mn : v4) + EPSF;
      float w0 = fmaxf(v0 - delta, 0.0f);
      float w1 = fmaxf(v1 - delta, 0.0f);
      float w2 = fmaxf(v2 - delta, 0.0f);
      float w3 = fmaxf(v3 - delta, 0.0f);
      float inv = 1.0f / (w0 + w1 + w2 + w3 + EPSF);
      w0 *= inv; w1 *= inv; w2 *= inv; w3 *= inv;

      float G[8];
      #pragma unroll
      for (int r = 0; r < 8; ++r) G[r] = bias_r[r];
      #pragma unroll
      for (int q = 0; q < 8; ++q) {
        #pragma unroll
        for (int p = 0; p < 4; ++p) {
          G[2 * p]     += red2[par][q][p][b][0];
          G[2 * p + 1] += red2[par][q][p][b][1];
        }
      }

      float cn0 = sigf(G[2]) * cs0 + sigf(G[0]) * tanhf(G[4]);
      float hn0 = sigf(G[6]) * tanhf(cn0);
      float cn1 = sigf(G[3]) * cs1 + sigf(G[1]) * tanhf(G[5]);
      float hn1 = sigf(G[7]) * tanhf(cn1);
      cs0 = cn0; cs1 = cn1;

      float m0 = w0 * qa0 + w1 * qa1 + w2 * qa2 + w3 * qa3;  // registers, no gather
      float m1 = w0 * qb0 + w1 * qb1 + w2 * qb2 + w3 * qb3;
      float ho0 = hn0 + m0, ho1 = hn1 + m1;
      po0 = ho0; po1 = ho1;  // becomes mem[i+1] value for future insertion

      if (kqu == 0) {
        v2f hov; hov[0] = ho0; hov[1] = ho1;
        st_lic_f32x2(ws + MEM4_F + (unsigned)(i + 1) * 32768u + hoff0, hov);
        asm volatile("s_waitcnt vmcnt(0)" ::: "memory");  // mem at LIC
        st_lic_u32(&flags[2 * g], (unsigned)(i + 1));
      } else if (kqu == 1) {
        v2f mv; mv[0] = m0; mv[1] = m1;
        *(v2f*)(ws + MSEQ4_F + (unsigned)i * 32768u + hoff0) = mv;  // out_gemm-only
      } else {
        st_lic_f32(ws + PSUM4_F + (unsigned)(i + 1) * 16384u + (unsigned)(g >> 2) * 256u
                   + (unsigned)b * 4u + (unsigned)(g & 3),
                   tanhf(ho0) * wt20 + tanhf(ho1) * wt21);
        asm volatile("s_waitcnt vmcnt(0)" ::: "memory");  // psum at LIC
        st_lic_u32(&flags[2 * g + 1], (unsigned)(i + 1));
      }
    }

    // ---- overlap: x-part of NEXT step's matvec (static xT4) ----
    if (i + 1 < T_N) {
      const v4f* xp = (const v4f*)(ws + XT4_F) + (unsigned)(i + 1) * 4096u
                      + (unsigned)(kqu * 8) * 64u + b;
      v4f xv[8];
      #pragma unroll
      for (int j = 0; j < 8; ++j) xv[j] = xp[j * 64];
      #pragma unroll
      for (int r = 0; r < 8; ++r) xacc[r] = 0.0f;
      #pragma unroll
      for (int j = 0; j < 8; ++j) {
        #pragma unroll
        for (int u = 0; u < 4; ++u) {
          float v = xv[j][u];
          const float* wr = &Wx[kqu * 32 + 4 * j + u][0];
          #pragma unroll
          for (int r = 0; r < 8; ++r) xacc[r] += v * wr[r];
        }
      }
    }
  }
}

// out[t,b,c] = sum_d feats[t,d,b]*fcwT[d,c] + fc_b[c];
// feats h-half == mem4[t+1], m-half == mseq4[t] (packed [k4][b][4]).
__launch_bounds__(256, 4)
__global__ void out_gemm(const float* __restrict__ ws, const float* __restrict__ fc_b,
                         float* __restrict__ out) {
  __shared__ float fw[64][16];
  const int t = blockIdx.x >> 2, cg = blockIdx.x & 3;
  const int tid = threadIdx.x, b = tid & 63, cs = (tid >> 6) * 4;
  float acc[4] = {0.0f, 0.0f, 0.0f, 0.0f};
  const v4f* hsrc = (const v4f*)(ws + MEM4_F) + (unsigned)(t + 1) * 8192u + b;
  const v4f* msrc = (const v4f*)(ws + MSEQ4_F) + (unsigned)t * 8192u + b;
  for (int half = 0; half < 2; ++half) {
    const v4f* src = half ? msrc : hsrc;
    for (int dt = 0; dt < 512; dt += 64) {
      __syncthreads();
      for (int u = tid; u < 1024; u += 256) {
        int dd = u >> 4, cc = u & 15;
        fw[dd][cc] = ws[FCWT_F + (unsigned)(half * 512 + dt + dd) * 64u + cg * 16 + cc];
      }
      __syncthreads();
      #pragma unroll 4
      for (int j = 0; j < 16; ++j) {
        v4f f4 = src[(unsigned)(dt / 4 + j) * 64u];
        #pragma unroll
        for (int u = 0; u < 4; ++u) {
          float f = f4[u];
          const float* wr = &fw[4 * j + u][cs];
          #pragma unroll
          for (int c4 = 0; c4 < 4; ++c4) acc[c4] += f * wr[c4];
        }
      }
    }
  }
  float* op = out + ((unsigned)t * 64u + b) * 64u + cg * 16 + cs;
  #pragma unroll
  for (int c4 = 0; c4 < 4; ++c4) op[c4] = acc[c4] + fc_b[cg * 16 + cs + c4];
}

extern "C" void kernel_launch(void* const* d_in, const int* in_sizes, int n_in,
                              void* d_out, int out_size, void* d_ws, size_t ws_size,
                              hipStream_t stream) {
  const float* x    = (const float*)d_in[0];
  const float* W_ih = (const float*)d_in[1];
  const float* W_hh = (const float*)d_in[2];
  const float* b_ih = (const float*)d_in[3];
  const float* b_hh = (const float*)d_in[4];
  const float* w_t  = (const float*)d_in[5];
  const float* fc_w = (const float*)d_in[6];
  const float* fc_b = (const float*)d_in[7];
  float* out = (float*)d_out;
  float* ws  = (float*)d_ws;

  if (ws_size < (size_t)TOT_F * 4u) {
    poison_k<<<(out_size + 255) / 256, 256, 0, stream>>>(out, out_size);
    return;
  }

  hipMemsetAsync(ws + MEM4_F, 0, (size_t)32768u * 4u, stream);     // mem[0] = 0
  hipMemsetAsync(ws + PSUM4_F, 0, (size_t)16384u * 4u, stream);    // psum plane 0
  hipMemsetAsync(ws + FLAG_F, 0, 512u * 4u, stream);               // flag pairs

  init_k<<<1040, 256, 0, stream>>>(x, fc_w, ws);
  lstm_main<<<256, 512, 0, stream>>>(W_ih, W_hh, b_ih, b_hh, w_t, ws);
  out_gemm<<<1024, 256, 0, stream>>>(ws, fc_b, out);
}

// Round 10
// 1686.020 us; speedup vs baseline: 1.5604x; 1.5604x over previous
//
#include <hip/hip_runtime.h>

// ---------------------------------------------------------------------------
// self_LSTM_sparse_attn — MI355X persistent-kernel, round 10.
//
// R9 post-mortem (REGRESSION 1790->2655us, VALUBusy 51->24%): splitting the
// flags and idling waves 3..7 opened a ~2us/step idle-spin window; ~1280
// spinning waves hammered the LIC flag lines and contended with the very
// stores they were waiting for. REVERTED to the R8 skeleton (tail replicated
// on all 8 waves, ONE flag published after the S2 vmcnt-drain, single-plane
// LDS). Kept exactly one R9 idea — register-carried gather: top-5 slots
// carry their memory VALUES (qa,qb) through the ins5 shifts; new entrant's
// value is ho(i-1) (registers po0,po1). The 4 random LIC gather loads are
// gone from every wave's tail; value-identical to the gather.
//
// Carried invariants (R5-R8-verified): cross-WG data write-once per step;
// cross-WG stores direct to LIC via sc0 sc1 (no fences anywhere); flag[g]
// stored only after the __syncthreads vmcnt drain of g's plane stores;
// per-wave producer wait (wave kqu's psum slots AND mem dims both produced
// by WGs [32kqu,32kqu+32), lane polls flag[32kqu+(b&31)]).
// Algorithm (R2-R8-verified): s_h cancels in attention weights; w <=4-sparse;
// WG g owns h dims {2g,2g+1}; mem[i] == h_out(i-1); incremental top-5.
// ---------------------------------------------------------------------------

#define T_N 256
#define B_N 64
#define I_N 256
#define H_N 512
#define C_N 64
#define EPSF 1e-7f

typedef float v4f __attribute__((ext_vector_type(4)));
typedef float v2f __attribute__((ext_vector_type(2)));

// ws layout (float offsets). Packed layouts: [..][k4][b][u] u=k&3.
#define XT4_F   0u          // [T][64][64][4]    x packed          (4,194,304)
#define MEM4_F  4194304u    // [T+1][128][64][4] h_out history     (8,421,376)
#define MSEQ4_F 12615680u   // [T][128][64][4]   m_seq             (8,388,608)
#define PSUM4_F 21004288u   // [T+1][64][64][4]  score partials, write-once (4,210,688)
#define FCWT_F  25214976u   // [2H][C] fc_w transposed             (65,536)
#define FLAG_F  25280512u   // [256] arrival flags, packed u32     (256)
#define TOT_F   25280768u

__device__ __forceinline__ float sigf(float x) { return 1.0f / (1.0f + expf(-x)); }

// direct-to-LIC (coherence point) ops — no fences needed anywhere.
__device__ __forceinline__ void st_lic_f32(float* p, float v) {
  asm volatile("global_store_dword %0, %1, off sc0 sc1" :: "v"(p), "v"(v) : "memory");
}
__device__ __forceinline__ void st_lic_f32x2(float* p, v2f v) {
  asm volatile("global_store_dwordx2 %0, %1, off sc0 sc1" :: "v"(p), "v"(v) : "memory");
}
__device__ __forceinline__ void st_lic_u32(unsigned* p, unsigned v) {
  asm volatile("global_store_dword %0, %1, off sc0 sc1" :: "v"(p), "v"(v) : "memory");
}
__device__ __forceinline__ unsigned ld_lic_u32(const unsigned* p) {
  unsigned r;
  asm volatile("global_load_dword %0, %1, off sc0 sc1\n\ts_waitcnt vmcnt(0)"
               : "=v"(r) : "v"(p) : "memory");
  return r;
}

// insert (s, a0, a1) into descending top-5; slots 0..3 carry values (qa,qb)
__device__ __forceinline__ void ins5v(float s, float a0, float a1,
    float& v0, float& v1, float& v2, float& v3, float& v4,
    float& qa0, float& qb0, float& qa1, float& qb1,
    float& qa2, float& qb2, float& qa3, float& qb3) {
  if (s > v4) {
    if (s > v0) {
      v4=v3; v3=v2; qa3=qa2; qb3=qb2; v2=v1; qa2=qa1; qb2=qb1;
      v1=v0; qa1=qa0; qb1=qb0; v0=s; qa0=a0; qb0=a1;
    } else if (s > v1) {
      v4=v3; v3=v2; qa3=qa2; qb3=qb2; v2=v1; qa2=qa1; qb2=qb1;
      v1=s; qa1=a0; qb1=a1;
    } else if (s > v2) {
      v4=v3; v3=v2; qa3=qa2; qb3=qb2; v2=s; qa2=a0; qb2=a1;
    } else if (s > v3) {
      v4=v3; v3=s; qa3=a0; qb3=a1;
    } else {
      v4=s;
    }
  }
}

__global__ void poison_k(float* out, int n) {
  int i = blockIdx.x * 256 + threadIdx.x;
  if (i < n) out[i] = __int_as_float(0x7fc00000);
}

// blocks 0..1023: x -> xT4 packed; blocks 1024..1039: fc_w -> fcwT[d][c]
__global__ void init_k(const float* __restrict__ x, const float* __restrict__ fc_w,
                       float* __restrict__ ws) {
  __shared__ float tile[64][65];
  const int blk = blockIdx.x, tid = threadIdx.x;
  if (blk < 1024) {
    const int t = blk >> 2, k0 = (blk & 3) * 64;
    for (int u = tid; u < 4096; u += 256) {
      int bb = u >> 6, kk = u & 63;
      tile[kk][bb] = x[((unsigned)t * 64u + bb) * 256u + k0 + kk];
    }
    __syncthreads();
    for (int u = tid; u < 4096; u += 256) {
      int kk = u >> 6, bb = u & 63;
      int k = k0 + kk;
      ws[XT4_F + (unsigned)t * 16384u + (unsigned)(k >> 2) * 256u
         + (unsigned)bb * 4u + (unsigned)(k & 3)] = tile[kk][bb];
    }
  } else {
    const int d0 = (blk - 1024) * 64;
    for (int u = tid; u < 4096; u += 256) {
      int cc = u >> 6, dd = u & 63;
      tile[dd][cc] = fc_w[(unsigned)cc * 1024u + d0 + dd];
    }
    __syncthreads();
    for (int u = tid; u < 4096; u += 256) {
      int dd = u >> 6, cc = u & 63;
      ws[FCWT_F + (unsigned)(d0 + dd) * 64u + cc] = tile[dd][cc];
    }
  }
}

__launch_bounds__(512, 1)
__global__ void lstm_main(const float* __restrict__ W_ih, const float* __restrict__ W_hh,
                          const float* __restrict__ b_ih, const float* __restrict__ b_hh,
                          const float* __restrict__ w_t, float* __restrict__ ws) {
  __shared__ float Wx[I_N][8];           // 8 KB  weight rows, LDS-resident
  __shared__ float Wh[H_N][8];           // 16 KB
  __shared__ float red2[8][4][B_N][2];   // 16 KB gate partials (row pairs)
  __shared__ float psum[8][B_N];         // 2 KB

  const int g = blockIdx.x;
  const int tid = threadIdx.x;
  const int b = tid & 63;
  const int kqu = __builtin_amdgcn_readfirstlane(tid >> 6);  // wave id 0..7

  unsigned int* flags = (unsigned int*)(ws + FLAG_F);

  // stage weights (resident all steps)
  for (int idx = tid; idx < 8 * I_N; idx += 512) {
    int rr = idx >> 8, k = idx & (I_N - 1);
    int grow = (rr >> 1) * H_N + 2 * g + (rr & 1);   // rr = gate*2 + jj
    Wx[k][rr] = W_ih[grow * I_N + k];
  }
  for (int idx = tid; idx < 8 * H_N; idx += 512) {
    int rr = idx >> 9, k = idx & (H_N - 1);
    int grow = (rr >> 1) * H_N + 2 * g + (rr & 1);
    Wh[k][rr] = W_hh[grow * H_N + k];
  }
  float bias_r[8];
  #pragma unroll
  for (int r = 0; r < 8; ++r) {
    int grow = (r >> 1) * H_N + 2 * g + (r & 1);
    bias_r[r] = b_ih[grow] + b_hh[grow];
  }
  const float wt20 = w_t[H_N + 2 * g];
  const float wt21 = w_t[H_N + 2 * g + 1];
  __syncthreads();

  // per-wave replicated state (bit-identical streams across waves)
  float cs0 = 0.0f, cs1 = 0.0f;                 // LSTM c-state
  float po0 = 0.0f, po1 = 0.0f;                 // ho(i-1) == mem[i] values (own dims)
  float v0 = -3e38f, v1 = -3e38f, v2 = -3e38f, v3 = -3e38f, v4 = -3e38f;
  float qa0 = 0, qb0 = 0, qa1 = 0, qb1 = 0, qa2 = 0, qb2 = 0, qa3 = 0, qb3 = 0;
  float mn = 3e38f;

  const unsigned hoff0 = (unsigned)(g >> 1) * 256u + (unsigned)b * 4u + (unsigned)((g & 1) * 2);

  // prologue: x-part of step 0's matvec (k-eighth per wave)
  float xacc[8];
  #pragma unroll
  for (int r = 0; r < 8; ++r) xacc[r] = 0.0f;
  {
    const v4f* xp = (const v4f*)(ws + XT4_F) + (unsigned)(kqu * 8) * 64u + b;
    v4f xv[8];
    #pragma unroll
    for (int j = 0; j < 8; ++j) xv[j] = xp[j * 64];
    #pragma unroll
    for (int j = 0; j < 8; ++j) {
      #pragma unroll
      for (int u = 0; u < 4; ++u) {
        float v = xv[j][u];
        const float* wr = &Wx[kqu * 32 + 4 * j + u][0];
        #pragma unroll
        for (int r = 0; r < 8; ++r) xacc[r] += v * wr[r];
      }
    }
  }

  for (int i = 0; i < T_N; ++i) {
    // ---- S0: per-wave producer wait. Wave kqu's psum slots AND mem dims
    // are both written exactly by WGs [32kqu, 32kqu+32). ----
    if (i > 0) {
      const unsigned* fp = flags + (kqu * 32 + (b & 31));
      while (ld_lic_u32(fp) < (unsigned)i) __builtin_amdgcn_s_sleep(1);
    }

    // ---- Phase A: batched vector loads; weights broadcast from LDS ----
    v4f pv[8];
    {
      const v4f* pp = (const v4f*)(ws + PSUM4_F) + (unsigned)i * 4096u
                      + (unsigned)(kqu * 8) * 64u + b;
      #pragma unroll
      for (int j = 0; j < 8; ++j) pv[j] = pp[j * 64];
    }
    v4f hv[16];
    {
      const v4f* hp = (const v4f*)(ws + MEM4_F) + (unsigned)i * 8192u
                      + (unsigned)(kqu * 16) * 64u + b;  // mem[i] == h_out(i-1)
      #pragma unroll
      for (int j = 0; j < 16; ++j) hv[j] = hp[j * 64];
    }
    float ps = 0.0f;
    #pragma unroll
    for (int j = 0; j < 8; ++j) ps += (pv[j][0] + pv[j][1]) + (pv[j][2] + pv[j][3]);
    psum[kqu][b] = ps;

    float acc[8];
    #pragma unroll
    for (int r = 0; r < 8; ++r) acc[r] = xacc[r];
    #pragma unroll
    for (int j = 0; j < 16; ++j) {
      #pragma unroll
      for (int u = 0; u < 4; ++u) {
        float v = hv[j][u];
        const float* wr = &Wh[kqu * 64 + 4 * j + u][0];
        #pragma unroll
        for (int r = 0; r < 8; ++r) acc[r] += v * wr[r];
      }
    }
    #pragma unroll
    for (int p = 0; p < 4; ++p) {
      red2[kqu][p][b][0] = acc[2 * p];
      red2[kqu][p][b][1] = acc[2 * p + 1];
    }
    __syncthreads();  // S1

    // ---- replicated tail (all 8 waves, bit-identical; no memory gather) ----
    float sc = ((psum[0][b] + psum[1][b]) + (psum[2][b] + psum[3][b]))
             + ((psum[4][b] + psum[5][b]) + (psum[6][b] + psum[7][b]));
    ins5v(sc, po0, po1, v0, v1, v2, v3, v4,
          qa0, qb0, qa1, qb1, qa2, qb2, qa3, qb3);
    mn = fminf(mn, sc);
    float delta = ((i + 1) <= 5 ? mn : v4) + EPSF;
    float w0 = fmaxf(v0 - delta, 0.0f);
    float w1 = fmaxf(v1 - delta, 0.0f);
    float w2 = fmaxf(v2 - delta, 0.0f);
    float w3 = fmaxf(v3 - delta, 0.0f);
    float inv = 1.0f / (w0 + w1 + w2 + w3 + EPSF);
    w0 *= inv; w1 *= inv; w2 *= inv; w3 *= inv;

    float G[8];
    #pragma unroll
    for (int r = 0; r < 8; ++r) G[r] = bias_r[r];
    #pragma unroll
    for (int q = 0; q < 8; ++q) {
      #pragma unroll
      for (int p = 0; p < 4; ++p) {
        G[2 * p]     += red2[q][p][b][0];
        G[2 * p + 1] += red2[q][p][b][1];
      }
    }

    float cn0 = sigf(G[2]) * cs0 + sigf(G[0]) * tanhf(G[4]);
    float hn0 = sigf(G[6]) * tanhf(cn0);
    float cn1 = sigf(G[3]) * cs1 + sigf(G[1]) * tanhf(G[5]);
    float hn1 = sigf(G[7]) * tanhf(cn1);
    cs0 = cn0; cs1 = cn1;

    float m0 = w0 * qa0 + w1 * qa1 + w2 * qa2 + w3 * qa3;  // registers, no gather
    float m1 = w0 * qb0 + w1 * qb1 + w2 * qb2 + w3 * qb3;
    float ho0 = hn0 + m0, ho1 = hn1 + m1;
    po0 = ho0; po1 = ho1;  // becomes mem[i+1] value for future insertions

    // disjoint store shares per wave
    if (kqu == 0) {
      v2f hov; hov[0] = ho0; hov[1] = ho1;
      st_lic_f32x2(ws + MEM4_F + (unsigned)(i + 1) * 32768u + hoff0, hov);
    } else if (kqu == 1) {
      v2f mv; mv[0] = m0; mv[1] = m1;
      *(v2f*)(ws + MSEQ4_F + (unsigned)i * 32768u + hoff0) = mv;  // out_gemm-only
    } else if (kqu == 2) {
      st_lic_f32(ws + PSUM4_F + (unsigned)(i + 1) * 16384u + (unsigned)(g >> 2) * 256u
                 + (unsigned)b * 4u + (unsigned)(g & 3),
                 tanhf(ho0) * wt20 + tanhf(ho1) * wt21);
    }
    __syncthreads();  // S2 — per-wave vmcnt(0) drain: all shares at LIC
    if (tid == 0) st_lic_u32(&flags[g], (unsigned)(i + 1));

    // ---- overlap: x-part of NEXT step's matvec (static xT4) ----
    if (i + 1 < T_N) {
      const v4f* xp = (const v4f*)(ws + XT4_F) + (unsigned)(i + 1) * 4096u
                      + (unsigned)(kqu * 8) * 64u + b;
      v4f xv[8];
      #pragma unroll
      for (int j = 0; j < 8; ++j) xv[j] = xp[j * 64];
      #pragma unroll
      for (int r = 0; r < 8; ++r) xacc[r] = 0.0f;
      #pragma unroll
      for (int j = 0; j < 8; ++j) {
        #pragma unroll
        for (int u = 0; u < 4; ++u) {
          float v = xv[j][u];
          const float* wr = &Wx[kqu * 32 + 4 * j + u][0];
          #pragma unroll
          for (int r = 0; r < 8; ++r) xacc[r] += v * wr[r];
        }
      }
    }
  }
}

// out[t,b,c] = sum_d feats[t,d,b]*fcwT[d,c] + fc_b[c];
// feats h-half == mem4[t+1], m-half == mseq4[t] (packed [k4][b][4]).
__launch_bounds__(256, 4)
__global__ void out_gemm(const float* __restrict__ ws, const float* __restrict__ fc_b,
                         float* __restrict__ out) {
  __shared__ float fw[64][16];
  const int t = blockIdx.x >> 2, cg = blockIdx.x & 3;
  const int tid = threadIdx.x, b = tid & 63, cs = (tid >> 6) * 4;
  float acc[4] = {0.0f, 0.0f, 0.0f, 0.0f};
  const v4f* hsrc = (const v4f*)(ws + MEM4_F) + (unsigned)(t + 1) * 8192u + b;
  const v4f* msrc = (const v4f*)(ws + MSEQ4_F) + (unsigned)t * 8192u + b;
  for (int half = 0; half < 2; ++half) {
    const v4f* src = half ? msrc : hsrc;
    for (int dt = 0; dt < 512; dt += 64) {
      __syncthreads();
      for (int u = tid; u < 1024; u += 256) {
        int dd = u >> 4, cc = u & 15;
        fw[dd][cc] = ws[FCWT_F + (unsigned)(half * 512 + dt + dd) * 64u + cg * 16 + cc];
      }
      __syncthreads();
      #pragma unroll 4
      for (int j = 0; j < 16; ++j) {
        v4f f4 = src[(unsigned)(dt / 4 + j) * 64u];
        #pragma unroll
        for (int u = 0; u < 4; ++u) {
          float f = f4[u];
          const float* wr = &fw[4 * j + u][cs];
          #pragma unroll
          for (int c4 = 0; c4 < 4; ++c4) acc[c4] += f * wr[c4];
        }
      }
    }
  }
  float* op = out + ((unsigned)t * 64u + b) * 64u + cg * 16 + cs;
  #pragma unroll
  for (int c4 = 0; c4 < 4; ++c4) op[c4] = acc[c4] + fc_b[cg * 16 + cs + c4];
}

extern "C" void kernel_launch(void* const* d_in, const int* in_sizes, int n_in,
                              void* d_out, int out_size, void* d_ws, size_t ws_size,
                              hipStream_t stream) {
  const float* x    = (const float*)d_in[0];
  const float* W_ih = (const float*)d_in[1];
  const float* W_hh = (const float*)d_in[2];
  const float* b_ih = (const float*)d_in[3];
  const float* b_hh = (const float*)d_in[4];
  const float* w_t  = (const float*)d_in[5];
  const float* fc_w = (const float*)d_in[6];
  const float* fc_b = (const float*)d_in[7];
  float* out = (float*)d_out;
  float* ws  = (float*)d_ws;

  if (ws_size < (size_t)TOT_F * 4u) {
    poison_k<<<(out_size + 255) / 256, 256, 0, stream>>>(out, out_size);
    return;
  }

  hipMemsetAsync(ws + MEM4_F, 0, (size_t)32768u * 4u, stream);     // mem[0] = 0
  hipMemsetAsync(ws + PSUM4_F, 0, (size_t)16384u * 4u, stream);    // psum plane 0
  hipMemsetAsync(ws + FLAG_F, 0, 256u * 4u, stream);               // flags

  init_k<<<1040, 256, 0, stream>>>(x, fc_w, ws);
  lstm_main<<<256, 512, 0, stream>>>(W_ih, W_hh, b_ih, b_hh, w_t, ws);
  out_gemm<<<1024, 256, 0, stream>>>(ws, fc_b, out);
}